// Round 1
// 7348.341 us; speedup vs baseline: 1.0150x; 1.0150x over previous
//
#include <hip/hip_runtime.h>
#include <cstdint>
#include <cstddef>

#define BB 32
#define HH 512
#define EE 256
#define VV 32000
#define TT 64
#define KDIM 1280    // 2H+E
#define NBLK_V 500   // VV/64
#define WREG 2304    // per-wave LDS region (floats)
#define WTS  65      // transposed W tile stride (floats); 65 -> ~2-way write conflicts (68 was 4-way)

__device__ __forceinline__ float sigf(float x) { return 1.0f / (1.0f + expf(-x)); }

// ---------------------------------------------------------------------------
// k_init: featT z-region (k<512) and h-region (k in [768,1280)) = h0[0] for
// both ping-pong buffers; c buffer A = c0[0]. featT layout: featT[k*32 + b].
// ---------------------------------------------------------------------------
__global__ __launch_bounds__(256) void k_init(const float* __restrict__ h0,
                                              const float* __restrict__ c0,
                                              float* __restrict__ fA,
                                              float* __restrict__ fB,
                                              float* __restrict__ cA) {
    int idx = blockIdx.x * 256 + threadIdx.x;   // 0..16383
    int kk = idx >> 5;                          // 0..511
    int b  = idx & 31;
    float zv = h0[b * HH + kk];
    fA[kk * BB + b] = zv;
    fB[kk * BB + b] = zv;
    fA[(768 + kk) * BB + b] = zv;
    fB[(768 + kk) * BB + b] = zv;
    cA[b * HH + kk] = c0[b * HH + kk];
}

// ---------------------------------------------------------------------------
// k_pre: gzT[j*32+b] = sum_{k<512} Wih[j][k] * z[b][k] + bih[j] + bhh[j].
// grid 32 blocks x 256 thr; block owns 64 j rows; 4 waves k-split (128 each).
// Outer-product: lane owns 4 j x 8 b; W transposed-staged in per-wave LDS.
// ---------------------------------------------------------------------------
__global__ __launch_bounds__(256) void k_pre(const float* __restrict__ Wih,
                                             const float* __restrict__ bih,
                                             const float* __restrict__ bhh,
                                             const float* __restrict__ fz,
                                             float* __restrict__ gzT) {
    __shared__ float lds[4 * WREG];
    const int tid = threadIdx.x;
    const int l = tid & 63;
    const int wu = tid >> 6;
    const int j0 = blockIdx.x * 64;
    const int js = l & 15;   // 4 j rows: r = js*4+i
    const int bg = l >> 4;   // 8 b:     b = bg*8+q
    float* R = &lds[wu * WREG];

    float acc[4][8];
#pragma unroll
    for (int i = 0; i < 4; ++i)
#pragma unroll
        for (int q = 0; q < 8; ++q) acc[i][q] = 0.f;

    for (int ch = 0; ch < 4; ++ch) {
        int kg0 = wu * 128 + ch * 32;
#pragma unroll
        for (int i = 0; i < 8; ++i) {
            int f4 = i * 64 + l;
            int r = f4 >> 3;
            int c4 = (f4 & 7) * 4;
            float4 w = *(const float4*)&Wih[(size_t)(j0 + r) * 768 + kg0 + c4];
            R[(c4 + 0) * WTS + r] = w.x;
            R[(c4 + 1) * WTS + r] = w.y;
            R[(c4 + 2) * WTS + r] = w.z;
            R[(c4 + 3) * WTS + r] = w.w;
        }
#pragma unroll 4
        for (int kk = 0; kk < 32; ++kk) {
            float4 wv = *(const float4*)&R[kk * WTS + js * 4];
            const float* fp = &fz[(kg0 + kk) * BB + bg * 8];
            float4 fa = *(const float4*)fp;
            float4 fb = *(const float4*)(fp + 4);
            float w4[4] = {wv.x, wv.y, wv.z, wv.w};
            float f8[8] = {fa.x, fa.y, fa.z, fa.w, fb.x, fb.y, fb.z, fb.w};
#pragma unroll
            for (int i = 0; i < 4; ++i)
#pragma unroll
                for (int q = 0; q < 8; ++q) acc[i][q] = fmaf(w4[i], f8[q], acc[i][q]);
        }
    }
#pragma unroll
    for (int i = 0; i < 4; ++i) {
        int r = js * 4 + i;
        *(float4*)&R[r * 36 + bg * 8] = make_float4(acc[i][0], acc[i][1], acc[i][2], acc[i][3]);
        *(float4*)&R[r * 36 + bg * 8 + 4] = make_float4(acc[i][4], acc[i][5], acc[i][6], acc[i][7]);
    }
    __syncthreads();
    {
        int j = tid >> 2;
        int bq = (tid & 3) * 8;
        float bias = bih[j0 + j] + bhh[j0 + j];
#pragma unroll
        for (int q = 0; q < 8; ++q) {
            float s = lds[0 * WREG + j * 36 + bq + q] + lds[1 * WREG + j * 36 + bq + q] +
                      lds[2 * WREG + j * 36 + bq + q] + lds[3 * WREG + j * 36 + bq + q];
            gzT[(size_t)(j0 + j) * BB + bq + q] = s + bias;
        }
    }
}

// ---------------------------------------------------------------------------
// k_prelog (NEW, runs once): lzT[v*32+b] = b_out[v] + sum_{k<512} Wout[v][k]*z[b][k].
// z (feat rows 0..511) is constant across all 64 steps, so the z-half of the
// logits GEMM is hoisted out of the time loop (cuts per-step K 1280 -> 768).
// Structure = old k_logits with 4 chunks (K=512, 4 waves x 128 k each).
// ---------------------------------------------------------------------------
__global__ __launch_bounds__(256) void k_prelog(
    const float* __restrict__ Wout, const float* __restrict__ bout,
    const float* __restrict__ fz, float* __restrict__ lzT) {
    __shared__ float lds[4 * WREG];
    const int tid = threadIdx.x;
    const int l = tid & 63;
    const int wu = tid >> 6;
    const int v0 = blockIdx.x * 64;
    const int vs = l & 15;   // 4 v rows: r = vs*4+i
    const int bg = l >> 4;   // 8 b:     b = bg*8+q
    float* R = &lds[wu * WREG];

    float acc[4][8];
#pragma unroll
    for (int i = 0; i < 4; ++i)
#pragma unroll
        for (int q = 0; q < 8; ++q) acc[i][q] = 0.f;

    for (int ch = 0; ch < 4; ++ch) {
        int kg0 = wu * 128 + ch * 32;
#pragma unroll
        for (int i = 0; i < 8; ++i) {
            int f4 = i * 64 + l;
            int r = f4 >> 3;
            int c4 = (f4 & 7) * 4;
            float4 w = *(const float4*)&Wout[(size_t)(v0 + r) * KDIM + kg0 + c4];
            R[(c4 + 0) * WTS + r] = w.x;
            R[(c4 + 1) * WTS + r] = w.y;
            R[(c4 + 2) * WTS + r] = w.z;
            R[(c4 + 3) * WTS + r] = w.w;
        }
#pragma unroll 4
        for (int kk = 0; kk < 32; ++kk) {
            float4 wv = *(const float4*)&R[kk * WTS + vs * 4];
            const float* fp = &fz[(kg0 + kk) * BB + bg * 8];
            float4 fa = *(const float4*)fp;
            float4 fb = *(const float4*)(fp + 4);
            float w4[4] = {wv.x, wv.y, wv.z, wv.w};
            float f8[8] = {fa.x, fa.y, fa.z, fa.w, fb.x, fb.y, fb.z, fb.w};
#pragma unroll
            for (int i = 0; i < 4; ++i)
#pragma unroll
                for (int q = 0; q < 8; ++q) acc[i][q] = fmaf(w4[i], f8[q], acc[i][q]);
        }
    }
#pragma unroll
    for (int i = 0; i < 4; ++i) {
        int r = vs * 4 + i;
        *(float4*)&R[r * 36 + bg * 8] = make_float4(acc[i][0], acc[i][1], acc[i][2], acc[i][3]);
        *(float4*)&R[r * 36 + bg * 8 + 4] = make_float4(acc[i][4], acc[i][5], acc[i][6], acc[i][7]);
    }
    __syncthreads();
    {
        int b = tid >> 3;
        int rg = tid & 7;
#pragma unroll
        for (int i = 0; i < 8; ++i) {
            int r = i * 8 + rg;
            float s = lds[0 * WREG + r * 36 + b] + lds[1 * WREG + r * 36 + b] +
                      lds[2 * WREG + r * 36 + b] + lds[3 * WREG + r * 36 + b] +
                      bout[v0 + r];
            lzT[(size_t)(v0 + r) * BB + b] = s;
        }
    }
}

// ---------------------------------------------------------------------------
// k_gates: per step t. grid 128: uc=blk>>2 (16 u of 512), bg4=blk&3 (8 b).
// Finalize argmax (t>0) or read y0; gates = gz + Wih[:,512:]*emb[y] + Whh*h.
// K=768 split 4 ways across waves (192 each, 6 chunks of 32).
// T14 async-STAGE: next chunk's W tile prefetched into regs before the inner
// FMA loop so global latency hides under compute (only ~2 waves/SIMD resident).
// ---------------------------------------------------------------------------
__global__ __launch_bounds__(256) void k_gates(
    int t, const int* __restrict__ y0, const float* __restrict__ emb,
    const float* __restrict__ Wih, const float* __restrict__ Whh,
    const float* __restrict__ gzT,
    const float* __restrict__ fCur, float* __restrict__ fNext,
    const float* __restrict__ cCur, float* __restrict__ cNext,
    const float* __restrict__ apv, const int* __restrict__ api) {
    __shared__ float lds[4 * WREG];
    const int tid = threadIdx.x;
    const int l = tid & 63;
    const int wu = tid >> 6;
    const int uc = blockIdx.x >> 2;
    const int bg4 = blockIdx.x & 3;
    const int b0 = bg4 * 8;
    const int js = l & 15;   // 4 rows: r = js*4+i
    const int bg = l >> 4;   // 2 b:    b = b0 + bg*2 + {0,1}
    const int rr = l >> 3;       // staging row-within-8
    const int c4 = (l & 7) * 4;  // staging col*4

    // ---- y for this block's 8 b's (SGPR via readlane)
    int yv0, yv1, yv2, yv3, yv4, yv5, yv6, yv7;
    if (t == 0) {
        yv0 = y0[b0 + 0]; yv1 = y0[b0 + 1]; yv2 = y0[b0 + 2]; yv3 = y0[b0 + 3];
        yv4 = y0[b0 + 4]; yv5 = y0[b0 + 5]; yv6 = y0[b0 + 6]; yv7 = y0[b0 + 7];
    } else {
        int bi = l >> 3;   // 8 lanes per b
        float best = -3.4e38f;
        int bidx = 0x7fffffff;
        for (int e = (l & 7); e < NBLK_V; e += 8) {
            float v = apv[(b0 + bi) * NBLK_V + e];
            int ix = api[(b0 + bi) * NBLK_V + e];
            if (v > best || (v == best && ix < bidx)) { best = v; bidx = ix; }
        }
#pragma unroll
        for (int d = 1; d < 8; d <<= 1) {
            float ov = __shfl_xor(best, d, 8);
            int oi = __shfl_xor(bidx, d, 8);
            if (ov > best || (ov == best && oi < bidx)) { best = ov; bidx = oi; }
        }
        yv0 = __builtin_amdgcn_readlane(bidx, 0);
        yv1 = __builtin_amdgcn_readlane(bidx, 8);
        yv2 = __builtin_amdgcn_readlane(bidx, 16);
        yv3 = __builtin_amdgcn_readlane(bidx, 24);
        yv4 = __builtin_amdgcn_readlane(bidx, 32);
        yv5 = __builtin_amdgcn_readlane(bidx, 40);
        yv6 = __builtin_amdgcn_readlane(bidx, 48);
        yv7 = __builtin_amdgcn_readlane(bidx, 56);
    }
    // per-lane emb row bases for the inner gather (bg selects the b-pair)
    int yA = (bg == 0) ? yv0 : (bg == 1) ? yv2 : (bg == 2) ? yv4 : yv6;
    int yB = (bg == 0) ? yv1 : (bg == 1) ? yv3 : (bg == 2) ? yv5 : yv7;
    const float* embA = emb + (size_t)yA * EE;
    const float* embB = emb + (size_t)yB * EE;

    float acc[4][2];
#pragma unroll
    for (int i = 0; i < 4; ++i) { acc[i][0] = 0.f; acc[i][1] = 0.f; }
    float* R = &lds[wu * WREG];

    // prologue prefetch (chunk 0)
    float4 pw[8];
    {
        int kgp = wu * 192;
#pragma unroll
        for (int i = 0; i < 8; ++i) {
            int r = i * 8 + rr;
            int j = uc * 16 + (r & 15) + 512 * (r >> 4);
            pw[i] = (kgp < 256)
                ? *(const float4*)&Wih[(size_t)j * 768 + 512 + kgp + c4]
                : *(const float4*)&Whh[(size_t)j * 512 + (kgp - 256) + c4];
        }
    }

    for (int ch = 0; ch < 6; ++ch) {
        int kg0 = wu * 192 + ch * 32;   // kappa in [0,768); <256: emb, else h
#pragma unroll
        for (int i = 0; i < 8; ++i) {
            int r = i * 8 + rr;
            R[(c4 + 0) * WTS + r] = pw[i].x;
            R[(c4 + 1) * WTS + r] = pw[i].y;
            R[(c4 + 2) * WTS + r] = pw[i].z;
            R[(c4 + 3) * WTS + r] = pw[i].w;
        }
        if (ch < 5) {
            int kg1 = kg0 + 32;
#pragma unroll
            for (int i = 0; i < 8; ++i) {
                int r = i * 8 + rr;
                int j = uc * 16 + (r & 15) + 512 * (r >> 4);
                pw[i] = (kg1 < 256)
                    ? *(const float4*)&Wih[(size_t)j * 768 + 512 + kg1 + c4]
                    : *(const float4*)&Whh[(size_t)j * 512 + (kg1 - 256) + c4];
            }
        }
        if (kg0 < 256) {
#pragma unroll 4
            for (int kk = 0; kk < 32; ++kk) {
                float4 wv = *(const float4*)&R[kk * WTS + js * 4];
                float f0 = embA[kg0 + kk];
                float f1 = embB[kg0 + kk];
                float w4[4] = {wv.x, wv.y, wv.z, wv.w};
#pragma unroll
                for (int i = 0; i < 4; ++i) {
                    acc[i][0] = fmaf(w4[i], f0, acc[i][0]);
                    acc[i][1] = fmaf(w4[i], f1, acc[i][1]);
                }
            }
        } else {
#pragma unroll 4
            for (int kk = 0; kk < 32; ++kk) {
                float4 wv = *(const float4*)&R[kk * WTS + js * 4];
                float2 hv = *(const float2*)&fCur[(768 + kg0 - 256 + kk) * BB + b0 + bg * 2];
                float w4[4] = {wv.x, wv.y, wv.z, wv.w};
#pragma unroll
                for (int i = 0; i < 4; ++i) {
                    acc[i][0] = fmaf(w4[i], hv.x, acc[i][0]);
                    acc[i][1] = fmaf(w4[i], hv.y, acc[i][1]);
                }
            }
        }
    }
    // partials: [r*8 + bl], bl = bg*2 + {0,1}
#pragma unroll
    for (int i = 0; i < 4; ++i) {
        int r = js * 4 + i;
        *(float2*)&R[r * 8 + bg * 2] = make_float2(acc[i][0], acc[i][1]);
    }
    __syncthreads();

    if (tid < 128) {
        int u = tid & 15;
        int bl = tid >> 4;   // 0..7
        float pre[4];
#pragma unroll
        for (int g = 0; g < 4; ++g) {
            int r = u + 16 * g;
            float s = lds[0 * WREG + r * 8 + bl] + lds[1 * WREG + r * 8 + bl] +
                      lds[2 * WREG + r * 8 + bl] + lds[3 * WREG + r * 8 + bl];
            int j = uc * 16 + u + 512 * g;
            pre[g] = s + gzT[(size_t)j * BB + b0 + bl];
        }
        float ig = sigf(pre[0]);
        float fg = sigf(pre[1]);
        float gg = tanhf(pre[2]);
        float og = sigf(pre[3]);
        int u_g = uc * 16 + u;
        int b = b0 + bl;
        float cp = cCur[b * HH + u_g];
        float cn = fg * cp + ig * gg;
        float hn = og * tanhf(cn);
        cNext[b * HH + u_g] = cn;
        fNext[(768 + u_g) * BB + b] = hn;
    }
    if (uc == 0) {
        int yv[8] = {yv0, yv1, yv2, yv3, yv4, yv5, yv6, yv7};
#pragma unroll
        for (int i = 0; i < 8; ++i)
            fNext[(512 + tid) * BB + b0 + i] = emb[(size_t)yv[i] * EE + tid];
    }
}

// ---------------------------------------------------------------------------
// k_logits: per-step K reduced to 768 (emb+h only; z-half folded into lzT).
// 500 blocks x 256 thr; block owns 64 vocab rows; 4 waves k-split (192 each,
// 6 chunks of 32). T14 register-prefetch pipeline on the Wout staging.
// Epilogue: cross-wave reduce + lzT (incl. bias), store, argmax partials.
// ---------------------------------------------------------------------------
__global__ __launch_bounds__(256) void k_logits(
    int t, const float* __restrict__ Wout, const float* __restrict__ lzT,
    const float* __restrict__ feat, float* __restrict__ outbuf, int direct,
    float* __restrict__ apv, int* __restrict__ api) {
    __shared__ float lds[4 * WREG];
    const int tid = threadIdx.x;
    const int l = tid & 63;
    const int wu = tid >> 6;
    const int v0 = blockIdx.x * 64;
    const int vs = l & 15;   // 4 v rows: r = vs*4+i
    const int bg = l >> 4;   // 8 b:     b = bg*8+q
    const int rr = l >> 3;       // staging row-within-8
    const int c4 = (l & 7) * 4;  // staging col*4
    float* R = &lds[wu * WREG];

    float acc[4][8];
#pragma unroll
    for (int i = 0; i < 4; ++i)
#pragma unroll
        for (int q = 0; q < 8; ++q) acc[i][q] = 0.f;

    // prologue prefetch (chunk 0); Wout cols 512 + kappa
    float4 pw[8];
    {
        int kgp = wu * 192;
#pragma unroll
        for (int i = 0; i < 8; ++i)
            pw[i] = *(const float4*)&Wout[(size_t)(v0 + i * 8 + rr) * KDIM + 512 + kgp + c4];
    }

    for (int ch = 0; ch < 6; ++ch) {
        int kg0 = wu * 192 + ch * 32;   // kappa in [0,768)
#pragma unroll
        for (int i = 0; i < 8; ++i) {
            int r = i * 8 + rr;
            R[(c4 + 0) * WTS + r] = pw[i].x;
            R[(c4 + 1) * WTS + r] = pw[i].y;
            R[(c4 + 2) * WTS + r] = pw[i].z;
            R[(c4 + 3) * WTS + r] = pw[i].w;
        }
        if (ch < 5) {
            int kg1 = kg0 + 32;
#pragma unroll
            for (int i = 0; i < 8; ++i)
                pw[i] = *(const float4*)&Wout[(size_t)(v0 + i * 8 + rr) * KDIM + 512 + kg1 + c4];
        }
#pragma unroll 4
        for (int kk = 0; kk < 32; ++kk) {
            float4 wv = *(const float4*)&R[kk * WTS + vs * 4];
            const float* fp = &feat[(512 + kg0 + kk) * BB + bg * 8];
            float4 fa = *(const float4*)fp;
            float4 fb = *(const float4*)(fp + 4);
            float w4[4] = {wv.x, wv.y, wv.z, wv.w};
            float f8[8] = {fa.x, fa.y, fa.z, fa.w, fb.x, fb.y, fb.z, fb.w};
#pragma unroll
            for (int i = 0; i < 4; ++i)
#pragma unroll
                for (int q = 0; q < 8; ++q) acc[i][q] = fmaf(w4[i], f8[q], acc[i][q]);
        }
    }
    // partials: [r*36 + b]
#pragma unroll
    for (int i = 0; i < 4; ++i) {
        int r = vs * 4 + i;
        *(float4*)&R[r * 36 + bg * 8] = make_float4(acc[i][0], acc[i][1], acc[i][2], acc[i][3]);
        *(float4*)&R[r * 36 + bg * 8 + 4] = make_float4(acc[i][4], acc[i][5], acc[i][6], acc[i][7]);
    }
    __syncthreads();

    // reduce across waves + lzT (bias folded) + store + argmax. b = tid>>3, rg = tid&7
    {
        int b = tid >> 3;
        int rg = tid & 7;
        float best = -3.4e38f;
        int bidx = 0x7fffffff;
#pragma unroll
        for (int i = 0; i < 8; ++i) {
            int r = i * 8 + rg;
            float s = lds[0 * WREG + r * 36 + b] + lds[1 * WREG + r * 36 + b] +
                      lds[2 * WREG + r * 36 + b] + lds[3 * WREG + r * 36 + b] +
                      lzT[(size_t)(v0 + r) * BB + b];
            if (!direct)
                outbuf[((size_t)t * BB + b) * VV + v0 + r] = s;
            else
                outbuf[((size_t)b * VV + v0 + r) * TT + t] = s;
            if (s > best) { best = s; bidx = v0 + r; }   // ascending r: keeps lowest
        }
#pragma unroll
        for (int d = 1; d < 8; d <<= 1) {
            float ov = __shfl_xor(best, d, 8);
            int oi = __shfl_xor(bidx, d, 8);
            if (ov > best || (ov == best && oi < bidx)) { best = ov; bidx = oi; }
        }
        if (rg == 0) {
            apv[b * NBLK_V + blockIdx.x] = best;
            api[b * NBLK_V + blockIdx.x] = bidx;
        }
    }
}

// ---------------------------------------------------------------------------
// Final transpose: staged (T,B,V) -> out (B,V,T), coalesced both sides.
// ---------------------------------------------------------------------------
__global__ __launch_bounds__(256) void k_trans(const float* __restrict__ staged,
                                               float* __restrict__ out) {
    __shared__ float lds[64 * 65];
    int bx = blockIdx.x;              // 0..15999
    int b = bx / NBLK_V;
    int v0 = (bx % NBLK_V) * 64;
    int tid = threadIdx.x;
    int vl = tid & 63;
    int tq = tid >> 6;
#pragma unroll
    for (int i = 0; i < 16; ++i) {
        int tt = tq * 16 + i;
        lds[tt * 65 + vl] = staged[((size_t)tt * BB + b) * VV + v0 + vl];
    }
    __syncthreads();
    int v2 = tid >> 2;
    int t0 = (tid & 3) * 16;
#pragma unroll
    for (int q = 0; q < 4; ++q) {
        float4 val;
        val.x = lds[(t0 + q * 4 + 0) * 65 + v2];
        val.y = lds[(t0 + q * 4 + 1) * 65 + v2];
        val.z = lds[(t0 + q * 4 + 2) * 65 + v2];
        val.w = lds[(t0 + q * 4 + 3) * 65 + v2];
        *(float4*)&out[((size_t)b * VV + v0 + v2) * TT + t0 + q * 4] = val;
    }
}

// ---------------------------------------------------------------------------
extern "C" void kernel_launch(void* const* d_in, const int* in_sizes, int n_in,
                              void* d_out, int out_size, void* d_ws, size_t ws_size,
                              hipStream_t stream) {
    const int* y0 = (const int*)d_in[0];
    const float* h0 = (const float*)d_in[1];
    const float* c0 = (const float*)d_in[2];
    const float* emb = (const float*)d_in[3];
    const float* Wih = (const float*)d_in[4];
    const float* Whh = (const float*)d_in[5];
    const float* bih = (const float*)d_in[6];
    const float* bhh = (const float*)d_in[7];
    const float* Wout = (const float*)d_in[8];
    const float* bout = (const float*)d_in[9];
    float* out = (float*)d_out;

    const size_t stagedFloats = (size_t)TT * BB * VV;   // 65,536,000
    const size_t smallBytes = (2 * (size_t)KDIM * BB + 2 * (size_t)BB * HH +
                               4 * HH * BB /*gzT*/ + (size_t)BB * NBLK_V +
                               (size_t)VV * BB /*lzT*/) * 4 +
                              (size_t)BB * NBLK_V * sizeof(int) + 256;
    const size_t needStaged = stagedFloats * 4 + smallBytes;
    int use_staged = (ws_size >= needStaged) ? 1 : 0;

    char* w = (char*)d_ws;
    float* staged = (float*)w;
    size_t off = use_staged ? stagedFloats * 4 : 0;
    float* fA = (float*)(w + off); off += (size_t)KDIM * BB * 4;
    float* fB = (float*)(w + off); off += (size_t)KDIM * BB * 4;
    float* cA = (float*)(w + off); off += (size_t)BB * HH * 4;
    float* cB = (float*)(w + off); off += (size_t)BB * HH * 4;
    float* gzT = (float*)(w + off); off += (size_t)4 * HH * BB * 4;
    float* apv = (float*)(w + off); off += (size_t)BB * NBLK_V * 4;
    int* api = (int*)(w + off); off += (size_t)BB * NBLK_V * sizeof(int);
    float* lzT = (float*)(w + off);

    k_init<<<64, 256, 0, stream>>>(h0, c0, fA, fB, cA);
    k_pre<<<32, 256, 0, stream>>>(Wih, bih, bhh, fA, gzT);
    k_prelog<<<NBLK_V, 256, 0, stream>>>(Wout, bout, fA, lzT);

    for (int t = 0; t < TT; ++t) {
        const float* fCur = (t & 1) ? fB : fA;
        float* fNext = (t & 1) ? fA : fB;
        const float* cCur = (t & 1) ? cB : cA;
        float* cNext = (t & 1) ? cA : cB;
        k_gates<<<128, 256, 0, stream>>>(t, y0, emb, Wih, Whh, gzT,
                                         fCur, fNext, cCur, cNext, apv, api);
        k_logits<<<NBLK_V, 256, 0, stream>>>(t, Wout, lzT, fNext,
                                             use_staged ? staged : out,
                                             use_staged ? 0 : 1, apv, api);
    }
    if (use_staged) k_trans<<<BB * NBLK_V, 256, 0, stream>>>(staged, out);
}

// Round 2
// 5264.500 us; speedup vs baseline: 1.4168x; 1.3958x over previous
//
#include <hip/hip_runtime.h>
#include <cstdint>
#include <cstddef>

#define BB 32
#define HH 512
#define EE 256
#define VV 32000
#define TT 64
#define KDIM 1280    // 2H+E
#define NBLK_V 500   // VV/64
#define WREG 2304    // per-wave LDS region (floats)
#define WTS  68      // transposed W tile stride; 68 = 0 mod 4 -> aligned b128 reads, conflict-free

__device__ __forceinline__ float sigf(float x) { return 1.0f / (1.0f + expf(-x)); }

// ---------------------------------------------------------------------------
// k_init: featT z-region (k<512) and h-region (k in [768,1280)) = h0[0] for
// both ping-pong buffers; c buffer A = c0[0]. featT layout: featT[k*32 + b].
// ---------------------------------------------------------------------------
__global__ __launch_bounds__(256) void k_init(const float* __restrict__ h0,
                                              const float* __restrict__ c0,
                                              float* __restrict__ fA,
                                              float* __restrict__ fB,
                                              float* __restrict__ cA) {
    int idx = blockIdx.x * 256 + threadIdx.x;   // 0..16383
    int kk = idx >> 5;                          // 0..511
    int b  = idx & 31;
    float zv = h0[b * HH + kk];
    fA[kk * BB + b] = zv;
    fB[kk * BB + b] = zv;
    fA[(768 + kk) * BB + b] = zv;
    fB[(768 + kk) * BB + b] = zv;
    cA[b * HH + kk] = c0[b * HH + kk];
}

// ---------------------------------------------------------------------------
// k_pre: gzT[j*32+b] = sum_{k<512} Wih[j][k] * z[b][k] + bih[j] + bhh[j].
// ---------------------------------------------------------------------------
__global__ __launch_bounds__(256) void k_pre(const float* __restrict__ Wih,
                                             const float* __restrict__ bih,
                                             const float* __restrict__ bhh,
                                             const float* __restrict__ fz,
                                             float* __restrict__ gzT) {
    __shared__ float lds[4 * WREG];
    const int tid = threadIdx.x;
    const int l = tid & 63;
    const int wu = tid >> 6;
    const int j0 = blockIdx.x * 64;
    const int js = l & 15;   // 4 j rows: r = js*4+i
    const int bg = l >> 4;   // 8 b:     b = bg*8+q
    float* R = &lds[wu * WREG];

    float acc[4][8];
#pragma unroll
    for (int i = 0; i < 4; ++i)
#pragma unroll
        for (int q = 0; q < 8; ++q) acc[i][q] = 0.f;

    for (int ch = 0; ch < 4; ++ch) {
        int kg0 = wu * 128 + ch * 32;
#pragma unroll
        for (int i = 0; i < 8; ++i) {
            int f4 = i * 64 + l;
            int r = f4 >> 3;
            int c4 = (f4 & 7) * 4;
            float4 w = *(const float4*)&Wih[(size_t)(j0 + r) * 768 + kg0 + c4];
            R[(c4 + 0) * WTS + r] = w.x;
            R[(c4 + 1) * WTS + r] = w.y;
            R[(c4 + 2) * WTS + r] = w.z;
            R[(c4 + 3) * WTS + r] = w.w;
        }
#pragma unroll 4
        for (int kk = 0; kk < 32; ++kk) {
            float4 wv = *(const float4*)&R[kk * WTS + js * 4];
            const float* fp = &fz[(kg0 + kk) * BB + bg * 8];
            float4 fa = *(const float4*)fp;
            float4 fb = *(const float4*)(fp + 4);
            float w4[4] = {wv.x, wv.y, wv.z, wv.w};
            float f8[8] = {fa.x, fa.y, fa.z, fa.w, fb.x, fb.y, fb.z, fb.w};
#pragma unroll
            for (int i = 0; i < 4; ++i)
#pragma unroll
                for (int q = 0; q < 8; ++q) acc[i][q] = fmaf(w4[i], f8[q], acc[i][q]);
        }
    }
#pragma unroll
    for (int i = 0; i < 4; ++i) {
        int r = js * 4 + i;
        *(float4*)&R[r * 36 + bg * 8] = make_float4(acc[i][0], acc[i][1], acc[i][2], acc[i][3]);
        *(float4*)&R[r * 36 + bg * 8 + 4] = make_float4(acc[i][4], acc[i][5], acc[i][6], acc[i][7]);
    }
    __syncthreads();
    {
        int j = tid >> 2;
        int bq = (tid & 3) * 8;
        float bias = bih[j0 + j] + bhh[j0 + j];
#pragma unroll
        for (int q = 0; q < 8; ++q) {
            float s = lds[0 * WREG + j * 36 + bq + q] + lds[1 * WREG + j * 36 + bq + q] +
                      lds[2 * WREG + j * 36 + bq + q] + lds[3 * WREG + j * 36 + bq + q];
            gzT[(size_t)(j0 + j) * BB + bq + q] = s + bias;
        }
    }
}

// ---------------------------------------------------------------------------
// k_prelog (once): lzT[v*32+b] = b_out[v] + sum_{k<512} Wout[v][k]*z[b][k].
// ---------------------------------------------------------------------------
__global__ __launch_bounds__(256) void k_prelog(
    const float* __restrict__ Wout, const float* __restrict__ bout,
    const float* __restrict__ fz, float* __restrict__ lzT) {
    __shared__ float lds[4 * WREG];
    const int tid = threadIdx.x;
    const int l = tid & 63;
    const int wu = tid >> 6;
    const int v0 = blockIdx.x * 64;
    const int vs = l & 15;
    const int bg = l >> 4;
    float* R = &lds[wu * WREG];

    float acc[4][8];
#pragma unroll
    for (int i = 0; i < 4; ++i)
#pragma unroll
        for (int q = 0; q < 8; ++q) acc[i][q] = 0.f;

    for (int ch = 0; ch < 4; ++ch) {
        int kg0 = wu * 128 + ch * 32;
#pragma unroll
        for (int i = 0; i < 8; ++i) {
            int f4 = i * 64 + l;
            int r = f4 >> 3;
            int c4 = (f4 & 7) * 4;
            float4 w = *(const float4*)&Wout[(size_t)(v0 + r) * KDIM + kg0 + c4];
            R[(c4 + 0) * WTS + r] = w.x;
            R[(c4 + 1) * WTS + r] = w.y;
            R[(c4 + 2) * WTS + r] = w.z;
            R[(c4 + 3) * WTS + r] = w.w;
        }
#pragma unroll 4
        for (int kk = 0; kk < 32; ++kk) {
            float4 wv = *(const float4*)&R[kk * WTS + vs * 4];
            const float* fp = &fz[(kg0 + kk) * BB + bg * 8];
            float4 fa = *(const float4*)fp;
            float4 fb = *(const float4*)(fp + 4);
            float w4[4] = {wv.x, wv.y, wv.z, wv.w};
            float f8[8] = {fa.x, fa.y, fa.z, fa.w, fb.x, fb.y, fb.z, fb.w};
#pragma unroll
            for (int i = 0; i < 4; ++i)
#pragma unroll
                for (int q = 0; q < 8; ++q) acc[i][q] = fmaf(w4[i], f8[q], acc[i][q]);
        }
    }
#pragma unroll
    for (int i = 0; i < 4; ++i) {
        int r = vs * 4 + i;
        *(float4*)&R[r * 36 + bg * 8] = make_float4(acc[i][0], acc[i][1], acc[i][2], acc[i][3]);
        *(float4*)&R[r * 36 + bg * 8 + 4] = make_float4(acc[i][4], acc[i][5], acc[i][6], acc[i][7]);
    }
    __syncthreads();
    {
        int b = tid >> 3;
        int rg = tid & 7;
#pragma unroll
        for (int i = 0; i < 8; ++i) {
            int r = i * 8 + rg;
            float s = lds[0 * WREG + r * 36 + b] + lds[1 * WREG + r * 36 + b] +
                      lds[2 * WREG + r * 36 + b] + lds[3 * WREG + r * 36 + b] +
                      bout[v0 + r];
            lzT[(size_t)(v0 + r) * BB + b] = s;
        }
    }
}

// ---------------------------------------------------------------------------
// k_gates v3: grid 256 (64 uc x 4 bgroups) x 256 thr -> ALL 256 CUs active
// (was 128 blocks = half GPU idle). Block owns 32 gate-rows (8 u x 4 gates)
// x 8 b. 4-wave k-split 192 (6 chunks of 32). Lane: 4 rows x 1 b.
// Argmax finalize: fixed-trip unroll-8 loop (8 loads in flight).
// ---------------------------------------------------------------------------
__global__ __launch_bounds__(256) void k_gates(
    int t, const int* __restrict__ y0, const float* __restrict__ emb,
    const float* __restrict__ Wih, const float* __restrict__ Whh,
    const float* __restrict__ gzT,
    const float* __restrict__ fCur, float* __restrict__ fNext,
    const float* __restrict__ cCur, float* __restrict__ cNext,
    const float* __restrict__ apv, const int* __restrict__ api) {
    __shared__ float lds[4 * WREG];
    const int tid = threadIdx.x;
    const int l = tid & 63;
    const int wu = tid >> 6;
    const int uc = blockIdx.x >> 2;          // 0..63, owns u in [uc*8, uc*8+8)
    const int bg4 = blockIdx.x & 3;
    const int b0 = bg4 * 8;
    const int js = l & 7;    // 4 rows: r = js*4+i  (r in [0,32))
    const int bg = l >> 3;   // 1 b:    b = b0 + bg
    const int rr = l >> 3;       // staging row-within-4 quadruple reuse is fine
    const int c4s = (l & 7) * 4; // staging col*4

    // ---- y for this block's 8 b's
    int yv0, yv1, yv2, yv3, yv4, yv5, yv6, yv7;
    if (t == 0) {
        yv0 = y0[b0 + 0]; yv1 = y0[b0 + 1]; yv2 = y0[b0 + 2]; yv3 = y0[b0 + 3];
        yv4 = y0[b0 + 4]; yv5 = y0[b0 + 5]; yv6 = y0[b0 + 6]; yv7 = y0[b0 + 7];
    } else {
        int bi = l >> 3;   // 8 lanes per b
        int e0 = l & 7;
        float best = -3.4e38f;
        int bidx = 0x7fffffff;
#pragma unroll 8
        for (int it = 0; it < 63; ++it) {
            int e = e0 + it * 8;
            if (e < NBLK_V) {
                float v = apv[(b0 + bi) * NBLK_V + e];
                int ix = api[(b0 + bi) * NBLK_V + e];
                if (v > best || (v == best && ix < bidx)) { best = v; bidx = ix; }
            }
        }
#pragma unroll
        for (int d = 1; d < 8; d <<= 1) {
            float ov = __shfl_xor(best, d, 8);
            int oi = __shfl_xor(bidx, d, 8);
            if (ov > best || (ov == best && oi < bidx)) { best = ov; bidx = oi; }
        }
        yv0 = __builtin_amdgcn_readlane(bidx, 0);
        yv1 = __builtin_amdgcn_readlane(bidx, 8);
        yv2 = __builtin_amdgcn_readlane(bidx, 16);
        yv3 = __builtin_amdgcn_readlane(bidx, 24);
        yv4 = __builtin_amdgcn_readlane(bidx, 32);
        yv5 = __builtin_amdgcn_readlane(bidx, 40);
        yv6 = __builtin_amdgcn_readlane(bidx, 48);
        yv7 = __builtin_amdgcn_readlane(bidx, 56);
    }
    // per-lane emb row base (one b per lane)
    int yA = (bg == 0) ? yv0 : (bg == 1) ? yv1 : (bg == 2) ? yv2 : (bg == 3) ? yv3
           : (bg == 4) ? yv4 : (bg == 5) ? yv5 : (bg == 6) ? yv6 : yv7;
    const float* embA = emb + (size_t)yA * EE;

    float acc[4];
#pragma unroll
    for (int i = 0; i < 4; ++i) acc[i] = 0.f;
    float* R = &lds[wu * WREG];

    // prologue prefetch (chunk 0): 32 rows x 32 k = 4 float4/lane
    float4 pw[4];
    {
        int kgp = wu * 192;
#pragma unroll
        for (int i = 0; i < 4; ++i) {
            int r = i * 8 + rr;
            int j = uc * 8 + (r & 7) + 512 * (r >> 3);
            pw[i] = (kgp < 256)
                ? *(const float4*)&Wih[(size_t)j * 768 + 512 + kgp + c4s]
                : *(const float4*)&Whh[(size_t)j * 512 + (kgp - 256) + c4s];
        }
    }

    for (int ch = 0; ch < 6; ++ch) {
        int kg0 = wu * 192 + ch * 32;   // kappa in [0,768); <256: emb, else h
#pragma unroll
        for (int i = 0; i < 4; ++i) {
            int r = i * 8 + rr;
            R[(c4s + 0) * WTS + r] = pw[i].x;
            R[(c4s + 1) * WTS + r] = pw[i].y;
            R[(c4s + 2) * WTS + r] = pw[i].z;
            R[(c4s + 3) * WTS + r] = pw[i].w;
        }
        if (ch < 5) {
            int kg1 = kg0 + 32;
#pragma unroll
            for (int i = 0; i < 4; ++i) {
                int r = i * 8 + rr;
                int j = uc * 8 + (r & 7) + 512 * (r >> 3);
                pw[i] = (kg1 < 256)
                    ? *(const float4*)&Wih[(size_t)j * 768 + 512 + kg1 + c4s]
                    : *(const float4*)&Whh[(size_t)j * 512 + (kg1 - 256) + c4s];
            }
        }
        if (kg0 < 256) {
#pragma unroll 4
            for (int kk = 0; kk < 32; ++kk) {
                float4 wv = *(const float4*)&R[kk * WTS + js * 4];
                float f0 = embA[kg0 + kk];
                acc[0] = fmaf(wv.x, f0, acc[0]);
                acc[1] = fmaf(wv.y, f0, acc[1]);
                acc[2] = fmaf(wv.z, f0, acc[2]);
                acc[3] = fmaf(wv.w, f0, acc[3]);
            }
        } else {
#pragma unroll 4
            for (int kk = 0; kk < 32; ++kk) {
                float4 wv = *(const float4*)&R[kk * WTS + js * 4];
                float hv = fCur[(768 + kg0 - 256 + kk) * BB + b0 + bg];
                acc[0] = fmaf(wv.x, hv, acc[0]);
                acc[1] = fmaf(wv.y, hv, acc[1]);
                acc[2] = fmaf(wv.z, hv, acc[2]);
                acc[3] = fmaf(wv.w, hv, acc[3]);
            }
        }
    }
    // partials: [r*9 + bg], r<32, bg<8 (stride 9 -> ~conflict-free)
#pragma unroll
    for (int i = 0; i < 4; ++i) {
        int r = js * 4 + i;
        R[r * 9 + bg] = acc[i];
    }
    __syncthreads();

    if (tid < 64) {
        int u = tid & 7;
        int bl = tid >> 3;   // 0..7
        float pre[4];
#pragma unroll
        for (int g = 0; g < 4; ++g) {
            int r = u + 8 * g;
            float s = lds[0 * WREG + r * 9 + bl] + lds[1 * WREG + r * 9 + bl] +
                      lds[2 * WREG + r * 9 + bl] + lds[3 * WREG + r * 9 + bl];
            int j = uc * 8 + u + 512 * g;
            pre[g] = s + gzT[(size_t)j * BB + b0 + bl];
        }
        float ig = sigf(pre[0]);
        float fg = sigf(pre[1]);
        float gg = tanhf(pre[2]);
        float og = sigf(pre[3]);
        int u_g = uc * 8 + u;
        int b = b0 + bl;
        float cp = cCur[b * HH + u_g];
        float cn = fg * cp + ig * gg;
        float hn = og * tanhf(cn);
        cNext[b * HH + u_g] = cn;
        fNext[(768 + u_g) * BB + b] = hn;
    }
    if (uc == 0) {
        int yv[8] = {yv0, yv1, yv2, yv3, yv4, yv5, yv6, yv7};
#pragma unroll
        for (int i = 0; i < 8; ++i)
            fNext[(512 + tid) * BB + b0 + i] = emb[(size_t)yv[i] * EE + tid];
    }
}

// ---------------------------------------------------------------------------
// k_logits v3: 500 blocks x 512 thr (8 waves). Block owns 64 vocab rows,
// K=768 split 8 waves x 96 (3 chunks of 32). 2 blocks/CU x 8 waves = 4
// waves/SIMD (was 2) for latency hiding. Register-prefetch W staging.
// Epilogue: 8-region reduce + lzT, store, argmax partials.
// ---------------------------------------------------------------------------
__global__ __launch_bounds__(512, 4) void k_logits(
    int t, const float* __restrict__ Wout, const float* __restrict__ lzT,
    const float* __restrict__ feat, float* __restrict__ outbuf, int direct,
    float* __restrict__ apv, int* __restrict__ api) {
    __shared__ float lds[8 * WREG];
    const int tid = threadIdx.x;
    const int l = tid & 63;
    const int wu = tid >> 6;     // 0..7
    const int v0 = blockIdx.x * 64;
    const int vs = l & 15;   // 4 v rows: r = vs*4+i
    const int bg = l >> 4;   // 8 b:     b = bg*8+q
    const int rr = l >> 3;       // staging row-within-8
    const int c4s = (l & 7) * 4; // staging col*4
    float* R = &lds[wu * WREG];

    float acc[4][8];
#pragma unroll
    for (int i = 0; i < 4; ++i)
#pragma unroll
        for (int q = 0; q < 8; ++q) acc[i][q] = 0.f;

    // prologue prefetch (chunk 0); Wout cols 512 + kappa
    float4 pw[8];
    {
        int kgp = wu * 96;
#pragma unroll
        for (int i = 0; i < 8; ++i)
            pw[i] = *(const float4*)&Wout[(size_t)(v0 + i * 8 + rr) * KDIM + 512 + kgp + c4s];
    }

    for (int ch = 0; ch < 3; ++ch) {
        int kg0 = wu * 96 + ch * 32;   // kappa in [0,768)
#pragma unroll
        for (int i = 0; i < 8; ++i) {
            int r = i * 8 + rr;
            R[(c4s + 0) * WTS + r] = pw[i].x;
            R[(c4s + 1) * WTS + r] = pw[i].y;
            R[(c4s + 2) * WTS + r] = pw[i].z;
            R[(c4s + 3) * WTS + r] = pw[i].w;
        }
        if (ch < 2) {
            int kg1 = kg0 + 32;
#pragma unroll
            for (int i = 0; i < 8; ++i)
                pw[i] = *(const float4*)&Wout[(size_t)(v0 + i * 8 + rr) * KDIM + 512 + kg1 + c4s];
        }
#pragma unroll 4
        for (int kk = 0; kk < 32; ++kk) {
            float4 wv = *(const float4*)&R[kk * WTS + vs * 4];
            const float* fp = &feat[(512 + kg0 + kk) * BB + bg * 8];
            float4 fa = *(const float4*)fp;
            float4 fb = *(const float4*)(fp + 4);
            float w4[4] = {wv.x, wv.y, wv.z, wv.w};
            float f8[8] = {fa.x, fa.y, fa.z, fa.w, fb.x, fb.y, fb.z, fb.w};
#pragma unroll
            for (int i = 0; i < 4; ++i)
#pragma unroll
                for (int q = 0; q < 8; ++q) acc[i][q] = fmaf(w4[i], f8[q], acc[i][q]);
        }
    }
    // partials: [r*36 + b]
#pragma unroll
    for (int i = 0; i < 4; ++i) {
        int r = vs * 4 + i;
        *(float4*)&R[r * 36 + bg * 8] = make_float4(acc[i][0], acc[i][1], acc[i][2], acc[i][3]);
        *(float4*)&R[r * 36 + bg * 8 + 4] = make_float4(acc[i][4], acc[i][5], acc[i][6], acc[i][7]);
    }
    __syncthreads();

    // reduce across 8 waves + lzT + store + argmax. b = tid>>4, rg = tid&15
    {
        int b = tid >> 4;
        int rg = tid & 15;
        float best = -3.4e38f;
        int bidx = 0x7fffffff;
#pragma unroll
        for (int i = 0; i < 4; ++i) {
            int r = i * 16 + rg;
            float s = lds[0 * WREG + r * 36 + b] + lds[1 * WREG + r * 36 + b] +
                      lds[2 * WREG + r * 36 + b] + lds[3 * WREG + r * 36 + b] +
                      lds[4 * WREG + r * 36 + b] + lds[5 * WREG + r * 36 + b] +
                      lds[6 * WREG + r * 36 + b] + lds[7 * WREG + r * 36 + b] +
                      lzT[(size_t)(v0 + r) * BB + b];
            if (!direct)
                outbuf[((size_t)t * BB + b) * VV + v0 + r] = s;
            else
                outbuf[((size_t)b * VV + v0 + r) * TT + t] = s;
            if (s > best) { best = s; bidx = v0 + r; }   // ascending r: keeps lowest
        }
#pragma unroll
        for (int d = 1; d < 16; d <<= 1) {
            float ov = __shfl_xor(best, d, 16);
            int oi = __shfl_xor(bidx, d, 16);
            if (ov > best || (ov == best && oi < bidx)) { best = ov; bidx = oi; }
        }
        if (rg == 0) {
            apv[b * NBLK_V + blockIdx.x] = best;
            api[b * NBLK_V + blockIdx.x] = bidx;
        }
    }
}

// ---------------------------------------------------------------------------
// Final transpose: staged (T,B,V) -> out (B,V,T), coalesced both sides.
// ---------------------------------------------------------------------------
__global__ __launch_bounds__(256) void k_trans(const float* __restrict__ staged,
                                               float* __restrict__ out) {
    __shared__ float lds[64 * 65];
    int bx = blockIdx.x;              // 0..15999
    int b = bx / NBLK_V;
    int v0 = (bx % NBLK_V) * 64;
    int tid = threadIdx.x;
    int vl = tid & 63;
    int tq = tid >> 6;
#pragma unroll
    for (int i = 0; i < 16; ++i) {
        int tt = tq * 16 + i;
        lds[tt * 65 + vl] = staged[((size_t)tt * BB + b) * VV + v0 + vl];
    }
    __syncthreads();
    int v2 = tid >> 2;
    int t0 = (tid & 3) * 16;
#pragma unroll
    for (int q = 0; q < 4; ++q) {
        float4 val;
        val.x = lds[(t0 + q * 4 + 0) * 65 + v2];
        val.y = lds[(t0 + q * 4 + 1) * 65 + v2];
        val.z = lds[(t0 + q * 4 + 2) * 65 + v2];
        val.w = lds[(t0 + q * 4 + 3) * 65 + v2];
        *(float4*)&out[((size_t)b * VV + v0 + v2) * TT + t0 + q * 4] = val;
    }
}

// ---------------------------------------------------------------------------
extern "C" void kernel_launch(void* const* d_in, const int* in_sizes, int n_in,
                              void* d_out, int out_size, void* d_ws, size_t ws_size,
                              hipStream_t stream) {
    const int* y0 = (const int*)d_in[0];
    const float* h0 = (const float*)d_in[1];
    const float* c0 = (const float*)d_in[2];
    const float* emb = (const float*)d_in[3];
    const float* Wih = (const float*)d_in[4];
    const float* Whh = (const float*)d_in[5];
    const float* bih = (const float*)d_in[6];
    const float* bhh = (const float*)d_in[7];
    const float* Wout = (const float*)d_in[8];
    const float* bout = (const float*)d_in[9];
    float* out = (float*)d_out;

    const size_t stagedFloats = (size_t)TT * BB * VV;   // 65,536,000
    const size_t smallBytes = (2 * (size_t)KDIM * BB + 2 * (size_t)BB * HH +
                               4 * HH * BB /*gzT*/ + (size_t)BB * NBLK_V +
                               (size_t)VV * BB /*lzT*/) * 4 +
                              (size_t)BB * NBLK_V * sizeof(int) + 256;
    const size_t needStaged = stagedFloats * 4 + smallBytes;
    int use_staged = (ws_size >= needStaged) ? 1 : 0;

    char* w = (char*)d_ws;
    float* staged = (float*)w;
    size_t off = use_staged ? stagedFloats * 4 : 0;
    float* fA = (float*)(w + off); off += (size_t)KDIM * BB * 4;
    float* fB = (float*)(w + off); off += (size_t)KDIM * BB * 4;
    float* cA = (float*)(w + off); off += (size_t)BB * HH * 4;
    float* cB = (float*)(w + off); off += (size_t)BB * HH * 4;
    float* gzT = (float*)(w + off); off += (size_t)4 * HH * BB * 4;
    float* apv = (float*)(w + off); off += (size_t)BB * NBLK_V * 4;
    int* api = (int*)(w + off); off += (size_t)BB * NBLK_V * sizeof(int);
    float* lzT = (float*)(w + off);

    k_init<<<64, 256, 0, stream>>>(h0, c0, fA, fB, cA);
    k_pre<<<32, 256, 0, stream>>>(Wih, bih, bhh, fA, gzT);
    k_prelog<<<NBLK_V, 256, 0, stream>>>(Wout, bout, fA, lzT);

    for (int t = 0; t < TT; ++t) {
        const float* fCur = (t & 1) ? fB : fA;
        float* fNext = (t & 1) ? fA : fB;
        const float* cCur = (t & 1) ? cB : cA;
        float* cNext = (t & 1) ? cA : cB;
        k_gates<<<256, 256, 0, stream>>>(t, y0, emb, Wih, Whh, gzT,
                                         fCur, fNext, cCur, cNext, apv, api);
        k_logits<<<NBLK_V, 512, 0, stream>>>(t, Wout, lzT, fNext,
                                             use_staged ? staged : out,
                                             use_staged ? 0 : 1, apv, api);
    }
    if (use_staged) k_trans<<<BB * NBLK_V, 256, 0, stream>>>(staged, out);
}